// Round 1
// baseline (26.587 us; speedup 1.0000x reference)
//
#include <hip/hip_runtime.h>

// Crop 128x128 patch per (b) at starts[b], bilinear x4 upsample to 512x512.
// out[b][c][y][x] = bilerp(patch, (y+0.5)/4-0.5, (x+0.5)/4-0.5), clamped.
// Exact match to jax.image.resize bilinear (renormalized edge weights ==
// clamped indices for this configuration).

#define PP   128
#define HH   512
#define WW   512
#define CC   3

__global__ __launch_bounds__(256) void crop_resize4x_kernel(
    const float* __restrict__ in,      // [B,C,H,W]
    const int*   __restrict__ starts,  // [B,2]
    float*       __restrict__ out,     // [B,C,H,W]
    int total_groups)                  // B*C*H*(W/4)
{
    const int stride = gridDim.x * blockDim.x;
    for (int t = blockIdx.x * blockDim.x + threadIdx.x; t < total_groups; t += stride) {
        // decompose: qx (W/4=128), y (512), bc (B*C)
        const int qx = t & 127;
        const int y  = (t >> 7) & 511;
        const int bc = t >> 16;            // 128*512 = 2^16
        const int b  = bc / 3;             // compiler magic-div

        const int s0 = starts[2 * b];
        const int s1 = starts[2 * b + 1];
        const float* patch = in + ((size_t)bc * HH + s0) * WW + s1;

        // vertical: y = 4*qy + ry
        const int qy = y >> 2;
        const int ry = y & 3;
        int y0, y1;
        float w1;  // weight of second (lower) row
        if (ry < 2) { y0 = qy - 1; y1 = qy;     w1 = (ry == 0) ? 0.625f : 0.875f; }
        else        { y0 = qy;     y1 = qy + 1; w1 = (ry == 2) ? 0.125f : 0.375f; }
        const float w0 = 1.0f - w1;
        y0 = max(y0, 0);
        y1 = min(y1, PP - 1);
        const float* r0 = patch + (size_t)y0 * WW;
        const float* r1 = patch + (size_t)y1 * WW;

        // horizontal: need input cols qx-1, qx, qx+1 (clamped)
        const int xa = max(qx - 1, 0);
        const int xb = qx;
        const int xc = min(qx + 1, PP - 1);

        const float va = w0 * r0[xa] + w1 * r1[xa];
        const float vb = w0 * r0[xb] + w1 * r1[xb];
        const float vc = w0 * r0[xc] + w1 * r1[xc];

        float4 o;
        o.x = 0.375f * va + 0.625f * vb;   // x%4==0: frac 0.625 from col qx-1/qx
        o.y = 0.125f * va + 0.875f * vb;   // x%4==1
        o.z = 0.875f * vb + 0.125f * vc;   // x%4==2
        o.w = 0.625f * vb + 0.375f * vc;   // x%4==3

        const size_t oidx = ((size_t)bc * HH + y) * WW + ((size_t)qx << 2);
        *reinterpret_cast<float4*>(out + oidx) = o;
    }
}

extern "C" void kernel_launch(void* const* d_in, const int* in_sizes, int n_in,
                              void* d_out, int out_size, void* d_ws, size_t ws_size,
                              hipStream_t stream) {
    const float* in     = (const float*)d_in[0];
    const int*   starts = (const int*)d_in[1];
    float*       out    = (float*)d_out;

    const int B = in_sizes[1] / 2;                     // starts is [B,2]
    const int total_groups = B * CC * HH * (WW / 4);   // one float4 per item

    const int block = 256;
    int grid = (total_groups + block - 1) / block;
    if (grid > 2048) grid = 2048;                      // grid-stride the rest

    crop_resize4x_kernel<<<grid, block, 0, stream>>>(in, starts, out, total_groups);
}

// Round 3
// 21.556 us; speedup vs baseline: 1.2334x; 1.2334x over previous
//
#include <hip/hip_runtime.h>

// Crop 128x128 patch per image at starts[b], bilinear x4 upsample to 512x512.
// Each thread computes a 4x4 output block (one 16B nontemporal store per row)
// from a 3x3 input neighborhood. Half-pixel-center bilinear, clamped indices
// (== jax.image.resize renormalized edge weights for this 4x config).

#define PP   128
#define HH   512
#define WW   512
#define CC   3

typedef float f32x4 __attribute__((ext_vector_type(4)));

__global__ __launch_bounds__(256) void crop_resize4x_blk_kernel(
    const float* __restrict__ in,      // [B,C,H,W]
    const int*   __restrict__ starts,  // [B,2]
    float*       __restrict__ out)     // [B,C,H,W]
{
    const int t  = blockIdx.x * blockDim.x + threadIdx.x;
    // decompose: qx (128), qy (128), bc (B*C)
    const int qx = t & 127;
    const int qy = (t >> 7) & 127;
    const int bc = t >> 14;
    const int b  = bc / 3;             // compiler magic-div, once per thread

    const int s0 = starts[2 * b];
    const int s1 = starts[2 * b + 1];
    const float* patch = in + ((size_t)bc * HH + s0) * WW + s1;

    // 3 input rows (clamped) and 3 input cols (clamped)
    const int ya = max(qy - 1, 0);
    const int yc = min(qy + 1, PP - 1);
    const int xa = max(qx - 1, 0);
    const int xc = min(qx + 1, PP - 1);

    const float* rA = patch + (size_t)ya * WW;
    const float* rB = patch + (size_t)qy * WW;
    const float* rC = patch + (size_t)yc * WW;

    // 9 input values
    const float aA = rA[xa], aB = rA[qx], aC = rA[xc];
    const float bA = rB[xa], bB = rB[qx], bC = rB[xc];
    const float cA = rC[xa], cB = rC[qx], cC = rC[xc];

    // vertical blends for the 4 output rows, per column
    // ry=0: .375*up + .625*mid ; ry=1: .125*up + .875*mid
    // ry=2: .875*mid + .125*dn ; ry=3: .625*mid + .375*dn
    float vA[4], vB[4], vC[4];
    vA[0] = 0.375f * aA + 0.625f * bA;
    vB[0] = 0.375f * aB + 0.625f * bB;
    vC[0] = 0.375f * aC + 0.625f * bC;
    vA[1] = 0.125f * aA + 0.875f * bA;
    vB[1] = 0.125f * aB + 0.875f * bB;
    vC[1] = 0.125f * aC + 0.875f * bC;
    vA[2] = 0.875f * bA + 0.125f * cA;
    vB[2] = 0.875f * bB + 0.125f * cB;
    vC[2] = 0.875f * bC + 0.125f * cC;
    vA[3] = 0.625f * bA + 0.375f * cA;
    vB[3] = 0.625f * bB + 0.375f * cB;
    vC[3] = 0.625f * bC + 0.375f * cC;

    float* orow = out + ((size_t)bc * HH + ((size_t)qy << 2)) * WW + ((size_t)qx << 2);

    #pragma unroll
    for (int ry = 0; ry < 4; ++ry) {
        f32x4 o;
        o.x = 0.375f * vA[ry] + 0.625f * vB[ry];
        o.y = 0.125f * vA[ry] + 0.875f * vB[ry];
        o.z = 0.875f * vB[ry] + 0.125f * vC[ry];
        o.w = 0.625f * vB[ry] + 0.375f * vC[ry];
        __builtin_nontemporal_store(o, reinterpret_cast<f32x4*>(orow + (size_t)ry * WW));
    }
}

extern "C" void kernel_launch(void* const* d_in, const int* in_sizes, int n_in,
                              void* d_out, int out_size, void* d_ws, size_t ws_size,
                              hipStream_t stream) {
    const float* in     = (const float*)d_in[0];
    const int*   starts = (const int*)d_in[1];
    float*       out    = (float*)d_out;

    const int B = in_sizes[1] / 2;                       // starts is [B,2]
    const int total_threads = B * CC * PP * PP;          // one 4x4 block each
    const int block = 256;
    const int grid = (total_threads + block - 1) / block;

    crop_resize4x_blk_kernel<<<grid, block, 0, stream>>>(in, starts, out);
}